// Round 1
// baseline (478.409 us; speedup 1.0000x reference)
//
#include <hip/hip_runtime.h>
#include <hip/hip_bf16.h>

#define IN_DIM 1024
#define DK 512
#define DV 512
#define NQ 8192
#define NKV 8192

typedef _Float16 f16x8 __attribute__((ext_vector_type(8)));
typedef _Float16 f16x4 __attribute__((ext_vector_type(4)));
typedef float f32x4 __attribute__((ext_vector_type(4)));

// ---------------- projection: out = A @ W^T + b -----------------------------
// Outputs in MFMA-fragment-major layout (frag = 64 lanes x 16 B = 1 KB):
//  Q'/K': frag fi = n_tile*16 + k_step; element [n = tile*16+l16][k = step*32+quad*8+j]
//  V'   : frag fi = (chunk*32 + dv_tile)*2 + kst;
//         element [key = chunk*64+kst*32+quad*8+j][dv = dv_tile*16+l16]
__global__ __launch_bounds__(256, 2) void proj_kernel(
    const float* __restrict__ qin, const float* __restrict__ kin, const float* __restrict__ vin,
    const float* __restrict__ Wq, const float* __restrict__ bq,
    const float* __restrict__ Wk, const float* __restrict__ bk,
    const float* __restrict__ Wv, const float* __restrict__ bv,
    _Float16* __restrict__ Qp, _Float16* __restrict__ Kp, _Float16* __restrict__ Vp)
{
    const int z = blockIdx.z;
    const float* A  = (z == 0) ? qin : (z == 1) ? kin : vin;
    const float* W  = (z == 0) ? Wq  : (z == 1) ? Wk  : Wv;
    const float* bi = (z == 0) ? bq  : (z == 1) ? bk  : bv;

    __shared__ __align__(16) char psm[73728];
    _Float16 (*As)[128][72] = (_Float16(*)[128][72])psm;           // [2][128][72]
    _Float16 (*Bs)[128][72] = (_Float16(*)[128][72])(psm + 36864);
    _Float16* trans = (_Float16*)psm;   // [128][152] = 38912 B, reused post-loop

    const int tid = threadIdx.x;
    const int rowbase = blockIdx.y * 128;
    const int colbase = blockIdx.x * 128;
    const int wave = tid >> 6;
    const int lane = tid & 63;
    const int quad = lane >> 4;
    const int l16  = lane & 15;
    const int wrow = (wave & 1) * 64;
    const int wcol = (wave >> 1) * 64;

    float4 ra[8], rb[8];
    auto ld = [&](int kc) {
#pragma unroll
        for (int i = 0; i < 8; ++i) {
            int idx = tid + i * 256;
            int row = idx >> 4, c4 = idx & 15;
            ra[i] = *(const float4*)&A[(size_t)(rowbase + row) * IN_DIM + kc * 64 + c4 * 4];
            rb[i] = *(const float4*)&W[(size_t)(colbase + row) * IN_DIM + kc * 64 + c4 * 4];
        }
    };
    auto st = [&](int buf) {
#pragma unroll
        for (int i = 0; i < 8; ++i) {
            int idx = tid + i * 256;
            int row = idx >> 4, c4 = idx & 15;
            f16x4 pa, pb;
            pa[0] = (_Float16)ra[i].x; pa[1] = (_Float16)ra[i].y;
            pa[2] = (_Float16)ra[i].z; pa[3] = (_Float16)ra[i].w;
            pb[0] = (_Float16)rb[i].x; pb[1] = (_Float16)rb[i].y;
            pb[2] = (_Float16)rb[i].z; pb[3] = (_Float16)rb[i].w;
            *(f16x4*)&As[buf][row][c4 * 4] = pa;
            *(f16x4*)&Bs[buf][row][c4 * 4] = pb;
        }
    };

    f32x4 acc[4][4];
#pragma unroll
    for (int r = 0; r < 4; ++r)
#pragma unroll
        for (int c = 0; c < 4; ++c) acc[r][c] = (f32x4)(0.0f);

    ld(0); st(0); ld(1);
    __syncthreads();

    for (int kc = 0; kc < 16; ++kc) {
        const int buf = kc & 1;
#pragma unroll
        for (int ks = 0; ks < 2; ++ks) {
            f16x8 af[4], bfr[4];
#pragma unroll
            for (int r = 0; r < 4; ++r)
                af[r] = *(const f16x8*)&As[buf][wrow + r * 16 + l16][ks * 32 + quad * 8];
#pragma unroll
            for (int c = 0; c < 4; ++c)
                bfr[c] = *(const f16x8*)&Bs[buf][wcol + c * 16 + l16][ks * 32 + quad * 8];
#pragma unroll
            for (int r = 0; r < 4; ++r)
#pragma unroll
                for (int c = 0; c < 4; ++c)
                    acc[r][c] = __builtin_amdgcn_mfma_f32_16x16x32_f16(af[r], bfr[c], acc[r][c], 0, 0, 0);
        }
        if (kc + 1 < 16) st(buf ^ 1);
        if (kc + 2 < 16) ld(kc + 2);
        __syncthreads();
    }
    // loop-ending barrier: LDS now dead, reuse as `trans`

    const int S = 152;   // row stride (f16); 304 B -> 2-way max bank aliasing
    if (z < 2) {
        _Float16* outp = (z == 0) ? Qp : Kp;
#pragma unroll
        for (int c = 0; c < 4; ++c) {
            int col = wcol + c * 16 + l16;          // local dk
            float bval = bi[colbase + col];
#pragma unroll
            for (int r = 0; r < 4; ++r)
#pragma unroll
                for (int g = 0; g < 4; ++g) {
                    int row = wrow + r * 16 + quad * 4 + g;   // local n (q or key)
                    trans[row * S + col] = (_Float16)(acc[r][c][g] + bval);
                }
        }
        __syncthreads();
#pragma unroll
        for (int i = 0; i < 2; ++i)
#pragma unroll
            for (int stp = 0; stp < 4; ++stp) {
                int tl = wave * 2 + i;
                f16x8 v = *(const f16x8*)&trans[(tl * 16 + l16) * S + stp * 32 + quad * 8];
                size_t fi = (size_t)((blockIdx.y * 8 + tl) * 16 + (blockIdx.x * 4 + stp));
                *(f16x8*)&outp[fi * 512 + lane * 8] = v;
            }
    } else {
        // stage TRANSPOSED: trans[dv][key] so V' frag reads are contiguous
#pragma unroll
        for (int c = 0; c < 4; ++c) {
            int dv = wcol + c * 16 + l16;
            float bval = bi[colbase + dv];
#pragma unroll
            for (int r = 0; r < 4; ++r)
#pragma unroll
                for (int g = 0; g < 4; ++g) {
                    int key = wrow + r * 16 + quad * 4 + g;
                    trans[dv * S + key] = (_Float16)(acc[r][c][g] + bval);
                }
        }
        __syncthreads();
#pragma unroll
        for (int i = 0; i < 2; ++i)
#pragma unroll
            for (int chl = 0; chl < 2; ++chl)
#pragma unroll
                for (int kst = 0; kst < 2; ++kst) {
                    int tdl = wave * 2 + i;
                    f16x8 v = *(const f16x8*)&trans[(tdl * 16 + l16) * S + chl * 64 + kst * 32 + quad * 8];
                    size_t fi = ((size_t)(blockIdx.y * 2 + chl) * 32 + (blockIdx.x * 8 + tdl)) * 2 + kst;
                    *(f16x8*)&Vp[fi * 512 + lane * 8] = v;
                }
    }
}

// ---- flash attention v2: 8 waves (2/SIMD), Q in LDS, no-drain barriers -----
// Block = 32 queries, 512 threads. Chunk = 128 keys (64 chunks).
// Wave w: S for key slice [ch*128 + w*16, +16); PV for dv slice [w*64, +64).
// Raw s_barrier + lgkmcnt-only waits keep kf/vf global loads in flight
// across barriers (no __syncthreads vmcnt(0) drain).
__global__ __launch_bounds__(512, 2) void flash_kernel(
    const _Float16* __restrict__ Qp, const _Float16* __restrict__ Kp,
    const _Float16* __restrict__ Vp, float* __restrict__ outp)
{
    __shared__ __align__(16) _Float16 Qls[16384];     // 32 KB: Q tile, frag-linear
    __shared__ __align__(16) _Float16 Ps[2][32][72];  // two 64-key P halves
    __shared__ float Smax2[32][12];                   // cols 0..7 used (8 waves)
    __shared__ float Ssum2[32][12];

    const int tid  = threadIdx.x;
    const int w    = tid >> 6;          // 0..7
    const int lane = tid & 63;
    const int quad = lane >> 4;
    const int l16  = lane & 15;
    const int qbase = blockIdx.x * 32;

    // ---- stage Q tile (32 frags = 32 KB); LDS layout == global frag layout
    {
        const f16x8* src = (const f16x8*)(Qp + (size_t)qbase * 512);
        f16x8* dst = (f16x8*)Qls;
#pragma unroll
        for (int i = 0; i < 4; ++i)
            dst[tid + i * 512] = src[tid + i * 512];
    }

    float mreg[2][4], lreg[2][4];
#pragma unroll
    for (int qt = 0; qt < 2; ++qt)
#pragma unroll
        for (int g = 0; g < 4; ++g) { mreg[qt][g] = -1e30f; lreg[qt][g] = 0.0f; }
    f32x4 oacc[2][4];
#pragma unroll
    for (int qt = 0; qt < 2; ++qt)
#pragma unroll
        for (int t = 0; t < 4; ++t) oacc[qt][t] = (f32x4)(0.0f);

    // ---- prologue: K frags for chunk 0 (wave's 16-key slice, full DK)
    const _Float16* kfp = Kp + (size_t)w * 16 * 512 + lane * 8;   // + ch*128*512
    f16x8 kf[16];
#pragma unroll
    for (int stp = 0; stp < 16; ++stp)
        kf[stp] = *(const f16x8*)(kfp + (size_t)stp * 512);

    // Qls visible to all waves before first S
    asm volatile("s_waitcnt lgkmcnt(0)" ::: "memory");
    __builtin_amdgcn_s_barrier();

    f16x8 vf[16];

    for (int ch = 0; ch < 64; ++ch) {
        // ---- issue V loads for THIS chunk (consumed in PV, past 2 barriers)
        const _Float16* vp = Vp + ((size_t)ch * 128 + w * 8) * 512 + lane * 8;
#pragma unroll
        for (int h = 0; h < 2; ++h)
#pragma unroll
            for (int t = 0; t < 4; ++t)
#pragma unroll
                for (int ks = 0; ks < 2; ++ks)
                    vf[h * 8 + t * 2 + ks] = *(const f16x8*)(vp + (size_t)(h * 64 + t * 2 + ks) * 512);

        // ---- S: 32 q x 16 keys (this wave's slice), Q frags from LDS
        f32x4 s0 = (f32x4)(0.0f), s1 = (f32x4)(0.0f);
        __builtin_amdgcn_s_setprio(1);
#pragma unroll
        for (int stp = 0; stp < 16; ++stp) {
            f16x8 q0 = *(const f16x8*)&Qls[(size_t)stp * 512 + lane * 8];
            f16x8 q1 = *(const f16x8*)&Qls[(size_t)(16 + stp) * 512 + lane * 8];
            s0 = __builtin_amdgcn_mfma_f32_16x16x32_f16(q0, kf[stp], s0, 0, 0, 0);
            s1 = __builtin_amdgcn_mfma_f32_16x16x32_f16(q1, kf[stp], s1, 0, 0, 0);
        }
        __builtin_amdgcn_s_setprio(0);

        // ---- slice row-max (16 lanes = 16 keys)
        float mx0[4], mx1[4];
#pragma unroll
        for (int g = 0; g < 4; ++g) {
            float m0 = s0[g], m1 = s1[g];
#pragma unroll
            for (int d = 1; d < 16; d <<= 1) {
                m0 = fmaxf(m0, __shfl_xor(m0, d));
                m1 = fmaxf(m1, __shfl_xor(m1, d));
            }
            mx0[g] = m0; mx1[g] = m1;
        }
        if (l16 == 0) {
#pragma unroll
            for (int g = 0; g < 4; ++g) {
                Smax2[quad * 4 + g][w]      = mx0[g];
                Smax2[16 + quad * 4 + g][w] = mx1[g];
            }
        }

        // ---- prefetch next K (kf consumed by S); stays in flight across B1/B2
        if (ch + 1 < 64) {
            const _Float16* kp = kfp + (size_t)(ch + 1) * 65536;
#pragma unroll
            for (int stp = 0; stp < 16; ++stp)
                kf[stp] = *(const f16x8*)(kp + (size_t)stp * 512);
        }

        asm volatile("s_waitcnt lgkmcnt(0)" ::: "memory");
        __builtin_amdgcn_s_barrier();      // B1: Smax2 ready (no vmcnt drain)

        // ---- combine max (8-way), alpha, exp, write P, slice sums
        float alpha0[4], alpha1[4];
#pragma unroll
        for (int g = 0; g < 4; ++g) {
            const int r0 = quad * 4 + g, r1 = r0 + 16;
            float4 a = *(const float4*)&Smax2[r0][0];
            float4 b = *(const float4*)&Smax2[r0][4];
            float mt0 = fmaxf(fmaxf(fmaxf(a.x, a.y), fmaxf(a.z, a.w)),
                              fmaxf(fmaxf(b.x, b.y), fmaxf(b.z, b.w)));
            float4 c = *(const float4*)&Smax2[r1][0];
            float4 d4 = *(const float4*)&Smax2[r1][4];
            float mt1 = fmaxf(fmaxf(fmaxf(c.x, c.y), fmaxf(c.z, c.w)),
                              fmaxf(fmaxf(d4.x, d4.y), fmaxf(d4.z, d4.w)));
            float mn0 = fmaxf(mreg[0][g], mt0);
            float mn1 = fmaxf(mreg[1][g], mt1);
            alpha0[g] = __expf(mreg[0][g] - mn0); mreg[0][g] = mn0;
            alpha1[g] = __expf(mreg[1][g] - mn1); mreg[1][g] = mn1;
            float p0 = __expf(s0[g] - mn0);
            float p1 = __expf(s1[g] - mn1);
            Ps[w >> 2][r0][(w & 3) * 16 + l16] = (_Float16)p0;
            Ps[w >> 2][r1][(w & 3) * 16 + l16] = (_Float16)p1;
            float t0 = p0, t1 = p1;
#pragma unroll
            for (int d = 1; d < 16; d <<= 1) {
                t0 += __shfl_xor(t0, d);
                t1 += __shfl_xor(t1, d);
            }
            if (l16 == 0) { Ssum2[r0][w] = t0; Ssum2[r1][w] = t1; }
        }

        asm volatile("s_waitcnt lgkmcnt(0)" ::: "memory");
        __builtin_amdgcn_s_barrier();      // B2: Ps/Ssum2 ready (no vmcnt drain)

        // ---- l update + O rescale
#pragma unroll
        for (int g = 0; g < 4; ++g) {
            const int r0 = quad * 4 + g, r1 = r0 + 16;
            float4 sa = *(const float4*)&Ssum2[r0][0];
            float4 sb = *(const float4*)&Ssum2[r0][4];
            float ls0 = (sa.x + sa.y) + (sa.z + sa.w) + (sb.x + sb.y) + (sb.z + sb.w);
            float4 sc = *(const float4*)&Ssum2[r1][0];
            float4 sd = *(const float4*)&Ssum2[r1][4];
            float ls1 = (sc.x + sc.y) + (sc.z + sc.w) + (sd.x + sd.y) + (sd.z + sd.w);
            lreg[0][g] = lreg[0][g] * alpha0[g] + ls0;
            lreg[1][g] = lreg[1][g] * alpha1[g] + ls1;
        }
#pragma unroll
        for (int t = 0; t < 4; ++t)
#pragma unroll
            for (int g = 0; g < 4; ++g) {
                oacc[0][t][g] *= alpha0[g];
                oacc[1][t][g] *= alpha1[g];
            }

        // ---- PV: P A-frags from LDS, V frags from registers
        __builtin_amdgcn_s_setprio(1);
#pragma unroll
        for (int kst = 0; kst < 4; ++kst) {
            f16x8 pa0 = *(const f16x8*)&Ps[kst >> 1][l16][(kst & 1) * 32 + quad * 8];
            f16x8 pa1 = *(const f16x8*)&Ps[kst >> 1][16 + l16][(kst & 1) * 32 + quad * 8];
            const int vb = (kst >> 1) * 8 + (kst & 1);
#pragma unroll
            for (int t = 0; t < 4; ++t) {
                oacc[0][t] = __builtin_amdgcn_mfma_f32_16x16x32_f16(pa0, vf[vb + t * 2], oacc[0][t], 0, 0, 0);
                oacc[1][t] = __builtin_amdgcn_mfma_f32_16x16x32_f16(pa1, vf[vb + t * 2], oacc[1][t], 0, 0, 0);
            }
        }
        __builtin_amdgcn_s_setprio(0);
    }

    // ---- epilogue: normalize + post-softmax scale, direct store
    const float norm = 0.044194173824159216f;   // 1/sqrt(512)
#pragma unroll
    for (int qt = 0; qt < 2; ++qt)
#pragma unroll
        for (int g = 0; g < 4; ++g) {
            const int row = qbase + qt * 16 + quad * 4 + g;
            const float sc = norm / lreg[qt][g];
#pragma unroll
            for (int t = 0; t < 4; ++t)
                outp[(size_t)row * 512 + w * 64 + t * 16 + l16] = oacc[qt][t][g] * sc;
        }
}

extern "C" void kernel_launch(void* const* d_in, const int* in_sizes, int n_in,
                              void* d_out, int out_size, void* d_ws, size_t ws_size,
                              hipStream_t stream) {
    const float* q  = (const float*)d_in[0];
    const float* k  = (const float*)d_in[1];
    const float* v  = (const float*)d_in[2];
    const float* Wq = (const float*)d_in[3];
    const float* bq = (const float*)d_in[4];
    const float* Wk = (const float*)d_in[5];
    const float* bk = (const float*)d_in[6];
    const float* Wv = (const float*)d_in[7];
    const float* bv = (const float*)d_in[8];

    _Float16* Qp = (_Float16*)d_ws;                 // 8 MB, frag-major
    _Float16* Kp = Qp + (size_t)NQ * DK;            // 8 MB, frag-major
    _Float16* Vp = Kp + (size_t)NKV * DK;           // 8 MB, frag-major
    float* outp = (float*)d_out;

    proj_kernel<<<dim3(DK / 128, NQ / 128, 3), 256, 0, stream>>>(
        q, k, v, Wq, bq, Wk, bk, Wv, bv, Qp, Kp, Vp);
    flash_kernel<<<dim3(NQ / 32), 512, 0, stream>>>(Qp, Kp, Vp, outp);
}